// Round 5
// baseline (208.219 us; speedup 1.0000x reference)
//
#include <hip/hip_runtime.h>

#pragma clang fp contract(off)

#define H_ 192
#define W_ 192
#define HW_ (192 * 192)
#define NSC 3
#define NCAND (NSC * HW_)
#define CCH 256
#define KMAX 2048
#define NBIN 4096
#define SEGCAP 1024  /* per-wave LDS segment buffer (keys); bench max segment ~30 */

// d_out layout (floats), in reference return order:
// keypoints [2048,2], descriptors [2048,256], scores [2048], det0/1/2 [192,192]
#define KP_OFF 0
#define DESC_OFF (KMAX * 2)
#define SC_OFF (DESC_OFF + KMAX * CCH)
#define DET_OFF (SC_OFF + KMAX)

typedef unsigned long long u64;
typedef unsigned int u32;

// ws layout (bytes):
//      0 : fin keys   u64[NCAND]      884736   (append order, unsorted)
// 884736 : cnts       u32[16]         64       [0]=nfin
// 884800 : ghist      u32[NBIN]       16384    (memset 0)
// memset covers cnts+ghist contiguously: 16448 B. No surv, no cursor, no
// global SARR: consumers recompute the 16 KB suffix scan in LDS and collect
// their bin's keys straight from fin (redundancy instead of synchronization —
// r1: never one-block a phase; r3: grid.sync ~45us/sync; r4: each dispatch
// boundary ~4us).
#define CNT_OFF 884736
#define GH_OFF 884800
#define ZERO_BYTES 16448

// Order-monotone, DISTRIBUTION-AWARE bin of the key's high word (positive
// ordered-float bits). det = max of 9 iid U[0,1) -> ~99.8% of mass in
// [0.5,1): give that range 2048 fine bins (mantissa bits 22..12); coarse
// monotone map below. Monotone at boundary: coarse max 0x3EF=1007 < 2048.
__device__ __forceinline__ u32 key_bin(u32 sb) {
    if (sb >= 0xBF800000u) return NBIN - 1;                        // det>=1: safety
    if (sb >= 0xBF000000u) return 2048u + ((sb >> 12) & 0x7FFu);   // det in [0.5,1)
    return (sb >> 20) & 0x7FFu;                                    // det in (0,0.5)
}

// Exact replica of the reference per-pixel math. FP contraction OFF for this
// TU -> float ops match numpy bit-for-bit. OOB taps read as 0.0, INCLUDING in
// the max: provably identical to the -inf-padded maxpool because scores>=0
// (zeros can't beat c>0; c==0 gives det=0 either way). Branchless.
__device__ __forceinline__ void newton_pixel(const float* __restrict__ sm, int i, int j,
                                             float& det, float& ki, float& kj, bool& valid) {
    float v[3][3];
#pragma unroll
    for (int a = 0; a < 3; ++a) {
#pragma unroll
        for (int b = 0; b < 3; ++b) {
            int ii = i + a - 1, jj = j + b - 1;
            bool in = (ii >= 0) && (ii < H_) && (jj >= 0) && (jj < W_);
            v[a][b] = in ? sm[ii * W_ + jj] : 0.0f;
        }
    }
    float c = v[1][1];
    float mx = v[0][0];
    mx = fmaxf(mx, v[0][1]); mx = fmaxf(mx, v[0][2]);
    mx = fmaxf(mx, v[1][0]); mx = fmaxf(mx, c);
    mx = fmaxf(mx, v[1][2]); mx = fmaxf(mx, v[2][0]);
    mx = fmaxf(mx, v[2][1]); mx = fmaxf(mx, v[2][2]);
    det = (mx == c) ? c : 0.0f;
    float di  = -0.5f * v[0][1] + 0.5f * v[2][1];
    float dj  = -0.5f * v[1][0] + 0.5f * v[1][2];
    float dii = v[0][1] - 2.0f * c + v[2][1];
    float djj = v[1][0] - 2.0f * c + v[1][2];
    float dij = 0.25f * v[0][0] - 0.25f * v[0][2] - 0.25f * v[2][0] + 0.25f * v[2][2];
    float dd = dii * djj - dij * dij;
    if (dd == 0.0f) dd = 1e-20f;
    float step_i = -(djj * di - dij * dj) / dd;
    float step_j = -(-dij * di + dii * dj) / dd;
    valid = (det != 0.0f) && (fabsf(step_i) < 0.5f) && (fabsf(step_j) < 0.5f);
    ki = valid ? ((float)i + step_i) : 0.0f;
    kj = valid ? ((float)j + step_j) : 0.0f;
    float i0 = floorf(ki), j0 = floorf(kj);
    valid = valid && (i0 >= 0.0f) && (j0 >= 0.0f) &&
            (i0 + 1.0f <= (float)(H_ - 1)) && (j0 + 1.0f <= (float)(W_ - 1));
}

__device__ __forceinline__ void decode_gid(u32 gid, int& s, int& i, int& j) {
    s = (int)(gid / HW_);
    int rem = (int)gid - s * HW_;
    i = rem / W_;
    j = rem - i * W_;
}

// Per-block redundant inclusive suffix scan of ghist into LDS:
// ls[b] = S[b] = #keys with bin >= b; ls[NBIN] = 0. ~16 KB L2-hot reads,
// ~2 us; cheaper than a dispatch boundary or a grid sync.
__device__ __forceinline__ void lds_suffix_scan(const u32* __restrict__ ghist,
                                                u32* ls, u32* lT) {
    int t = threadIdx.x;
    u32 chunk[16];
    u32 acc = 0;
#pragma unroll
    for (int k = 15; k >= 0; --k) {
        acc += ghist[t * 16 + k];
        chunk[k] = acc;  // suffix within chunk
    }
    lT[t] = acc;
    __syncthreads();
    // inclusive suffix scan of 256 chunk totals (Hillis-Steele)
    for (int off = 1; off < 256; off <<= 1) {
        u32 v = lT[t] + ((t + off < 256) ? lT[t + off] : 0u);
        __syncthreads();
        lT[t] = v;
        __syncthreads();
    }
    u32 add = (t < 255) ? lT[t + 1] : 0u;  // exclusive suffix of later chunks
#pragma unroll
    for (int k = 0; k < 16; ++k) ls[t * 16 + k] = chunk[k] + add;
    if (t == 0) ls[NBIN] = 0;
    __syncthreads();
}

// Kernel 1: per-pixel NMS/Newton; det maps; append valid keys; global-atomic
// score-bin histogram (~12k valid keys over ~2k hot bins -> no contention).
__global__ __launch_bounds__(256) void cand_kernel(
    const float* __restrict__ s0, const float* __restrict__ s1, const float* __restrict__ s2,
    float* __restrict__ out, u64* __restrict__ fin, u32* __restrict__ cnts,
    u32* __restrict__ ghist) {
    __shared__ u32 lcnt, base;
    int tid = threadIdx.x;
    if (tid == 0) lcnt = 0;
    __syncthreads();
    int t = blockIdx.x * 256 + tid;
    bool valid = false;
    u64 key = 0;
    {
        int s, i, j;
        decode_gid((u32)t, s, i, j);
        const float* sm = (s == 0) ? s0 : (s == 1) ? s1 : s2;
        float det, ki, kj;
        newton_pixel(sm, i, j, det, ki, kj, valid);
        out[DET_OFF + t] = det;
        if (valid) {
            u32 sb = __float_as_uint(det) | 0x80000000u;  // det>0: ordered bits
            key = ((u64)sb << 32) | (u64)(0xFFFFFFFFu - (u32)t);  // ties: lower idx first
            atomicAdd(&ghist[key_bin(sb)], 1u);
        }
    }
    u32 lpos = 0;
    if (valid) lpos = atomicAdd(&lcnt, 1u);
    __syncthreads();
    if (tid == 0 && lcnt > 0) base = atomicAdd(&cnts[0], lcnt);
    __syncthreads();
    if (valid) fin[base + lpos] = key;
}

// Kernel 2 (scan+scatter+rank+gather in one): one WAVE per slot r (4/block).
// Block recomputes the suffix scan in LDS. Each wave binary-searches the bin
// whose rank segment [S[b+1],S[b]) contains r, collects that bin's keys
// DIRECTLY from fin (lane-strided scan, L1/L2-hot: all 4 waves read the same
// ~96 KB) into a per-wave LDS buffer, all-pairs-ranks the ~13-key segment
// (distinct keys -> ranks are a permutation: exactly one match), recomputes
// the winner's newton state, and does the bilinear gather + L2-normalize.
// Overflow (segment > SEGCAP) falls back to wave-parallel threshold
// max-extraction: always correct, never hit on sane distributions.
__global__ __launch_bounds__(256) void output_kernel(
    const u64* __restrict__ fin, const u32* __restrict__ ghist,
    const float* __restrict__ s0, const float* __restrict__ s1, const float* __restrict__ s2,
    const float* __restrict__ f0, const float* __restrict__ f1, const float* __restrict__ f2,
    float* __restrict__ out) {
    __shared__ u32 ls[NBIN + 1];
    __shared__ u32 lT[256];
    __shared__ u64 seg[4][SEGCAP];
    __shared__ u32 segcnt[4];
    lds_suffix_scan(ghist, ls, lT);
    int tid = threadIdx.x;
    int lane = tid & 63;
    int w = tid >> 6;
    int r = blockIdx.x * 4 + w;
    u32 n = ls[0];  // total valid keys (== cnts[0])
    u32 nwin = (n < KMAX) ? n : KMAX;
    if ((u32)r >= nwin) {  // padding row (wave-uniform; no more block barriers)
#pragma unroll
        for (int k = 0; k < 4; ++k) out[DESC_OFF + r * CCH + k * 64 + lane] = 0.0f;
        if (lane == 0) {
            out[SC_OFF + r] = 0.0f;
            out[KP_OFF + r * 2 + 0] = 0.0f;
            out[KP_OFF + r * 2 + 1] = 0.0f;
        }
        return;
    }
    // binary search: largest b with S[b] > r  (S non-increasing, S[0]=n>r, S[NBIN]=0)
    u32 blo = 0, bhi = NBIN;
    while (bhi - blo > 1) {
        u32 mid = (blo + bhi) >> 1;
        if (ls[mid] > (u32)r) blo = mid; else bhi = mid;
    }
    u32 b = blo;
    u32 seglo = ls[b + 1], seghi = ls[b];  // S[b+1] <= r < S[b]
    u32 segsz = seghi - seglo;
    if (lane == 0) segcnt[w] = 0;
    __builtin_amdgcn_wave_barrier();
    u64 key;
    if (segsz <= SEGCAP) {
        // collect this bin's keys from fin (lane-strided, coalesced u64 loads)
        for (u32 p = (u32)lane; p < n; p += 64) {
            u64 k = fin[p];
            if (key_bin((u32)(k >> 32)) == b) {
                u32 pos = atomicAdd(&segcnt[w], 1u);
                seg[w][pos] = k;
            }
        }
        __builtin_amdgcn_wave_barrier();
        __asm__ volatile("s_waitcnt lgkmcnt(0)");  // LDS atomics/stores visible wave-wide
        // exact rank within segment: rank = seglo + #{segment keys > mine}
        u64 mykey = 0;
        bool mine = false;
        for (u32 idx = (u32)lane; idx < segsz; idx += 64) {
            u64 k = seg[w][idx];
            u32 rk = seglo;
            for (u32 q = 0; q < segsz; ++q) rk += (seg[w][q] > k) ? 1u : 0u;
            if (rk == (u32)r) { mykey = k; mine = true; }
        }
        u64 bal = __ballot(mine);
        int src = __ffsll((unsigned long long)bal) - 1;
        u32 klo = (u32)__shfl((int)(u32)(mykey & 0xFFFFFFFFull), src, 64);
        u32 khi = (u32)__shfl((int)(u32)(mykey >> 32), src, 64);
        key = ((u64)khi << 32) | (u64)klo;
    } else {
        // fallback: (r-seglo+1)-fold wave-parallel max-extraction below a
        // descending threshold. O((r-seglo) * n/64); correctness-only path.
        u32 t_rank = (u32)r - seglo;
        u64 cur = 0xFFFFFFFFFFFFFFFFull;
        for (u32 it = 0; it <= t_rank; ++it) {
            u64 best = 0;
            for (u32 p = (u32)lane; p < n; p += 64) {
                u64 k = fin[p];
                if (key_bin((u32)(k >> 32)) == b && k < cur && k > best) best = k;
            }
#pragma unroll
            for (int o = 1; o < 64; o <<= 1) {
                u32 blo2 = (u32)__shfl_xor((int)(u32)(best & 0xFFFFFFFFull), o, 64);
                u32 bhi2 = (u32)__shfl_xor((int)(u32)(best >> 32), o, 64);
                u64 other = ((u64)bhi2 << 32) | (u64)blo2;
                if (other > best) best = other;
            }
            cur = best;
        }
        key = cur;
    }
    // recompute newton state for the winner (9 broadcast loads, all lanes)
    u32 gid = 0xFFFFFFFFu - (u32)(key & 0xFFFFFFFFull);
    int s, i, j;
    decode_gid(gid, s, i, j);
    const float* sm = (s == 0) ? s0 : (s == 1) ? s1 : s2;
    float det, ki, kj;
    bool valid;
    newton_pixel(sm, i, j, det, ki, kj, valid);
    // bilinear gather + normalize: lane owns channels {lane, +64, +128, +192}
    const float* feat = (s == 0) ? f0 : (s == 1) ? f1 : f2;
    int i0 = (int)floorf(ki), j0 = (int)floorf(kj);
    float wi = ki - (float)i0;
    float wj = kj - (float)j0;
    const float* p = feat + (size_t)lane * HW_ + i0 * W_ + j0;
    float d[4];
    float sq = 0.0f;
#pragma unroll
    for (int k = 0; k < 4; ++k) {
        const float* q = p + (size_t)k * 64 * HW_;
        float f00 = q[0], f01 = q[1], f10 = q[W_], f11 = q[W_ + 1];
        d[k] = f00 * (1.0f - wi) * (1.0f - wj) + f01 * (1.0f - wi) * wj +
               f10 * wi * (1.0f - wj) + f11 * wi * wj;
        sq += d[k] * d[k];
    }
#pragma unroll
    for (int o = 1; o < 64; o <<= 1) sq += __shfl_xor(sq, o, 64);
    float norm = fmaxf(sqrtf(sq), 1e-12f);
#pragma unroll
    for (int k = 0; k < 4; ++k)
        out[DESC_OFF + r * CCH + k * 64 + lane] = d[k] / norm;
    if (lane == 0) {
        float x = kj, y = ki;
#pragma unroll
        for (int u = 0; u < 4; ++u) { x = x * 2.0f + 0.5f; y = y * 2.0f + 0.5f; }
        out[SC_OFF + r] = det;
        out[KP_OFF + r * 2 + 0] = x;  // (x=col, y=row)
        out[KP_OFF + r * 2 + 1] = y;
    }
}

extern "C" void kernel_launch(void* const* d_in, const int* in_sizes, int n_in,
                              void* d_out, int out_size, void* d_ws, size_t ws_size,
                              hipStream_t stream) {
    const float* f0 = (const float*)d_in[0];
    const float* f1 = (const float*)d_in[1];
    const float* f2 = (const float*)d_in[2];
    const float* s0 = (const float*)d_in[3];
    const float* s1 = (const float*)d_in[4];
    const float* s2 = (const float*)d_in[5];
    float* out = (float*)d_out;

    char* ws = (char*)d_ws;
    u64* fin = (u64*)ws;
    u32* cnts = (u32*)(ws + CNT_OFF);
    u32* ghist = (u32*)(ws + GH_OFF);

    // zero cnts + ghist in one contiguous memset (16 KB)
    hipMemsetAsync(ws + CNT_OFF, 0, ZERO_BYTES, stream);
    cand_kernel<<<NCAND / 256, 256, 0, stream>>>(s0, s1, s2, out, fin, cnts, ghist);
    output_kernel<<<KMAX / 4, 256, 0, stream>>>(fin, ghist, s0, s1, s2, f0, f1, f2, out);
}

// Round 6
// 156.370 us; speedup vs baseline: 1.3316x; 1.3316x over previous
//
#include <hip/hip_runtime.h>

#pragma clang fp contract(off)

#define H_ 192
#define W_ 192
#define HW_ (192 * 192)
#define NSC 3
#define NCAND (NSC * HW_)
#define CCH 256
#define KMAX 2048
#define NBIN 4096

// d_out layout (floats), in reference return order:
// keypoints [2048,2], descriptors [2048,256], scores [2048], det0/1/2 [192,192]
#define KP_OFF 0
#define DESC_OFF (KMAX * 2)
#define SC_OFF (DESC_OFF + KMAX * CCH)
#define DET_OFF (SC_OFF + KMAX)

typedef unsigned long long u64;
typedef unsigned int u32;

// ws layout (bytes):
//      0 : fin keys   u64[NCAND]      884736
// 884736 : cnts       u32[16]         64      [0]=nfin
// 884800 : ghist      u32[NBIN]       16384   (memset 0)
// 901184 : cursor     u32[NBIN]       16384   (memset 0; zero-based per-bin)
// 917568 : surv       u64[NCAND]      884736  (bin-grouped keys)
// memset covers cnts+ghist+cursor contiguously: 64+16384+16384 = 32832 B.
// No slot array, no global SARR: consumers recompute the 16 KB suffix scan in
// LDS. Session ledger: r1 one-block fusion +62us; r3 grid.sync ~45us/sync;
// r4 this structure = 157.2us (best); r5 per-wave fin-scan fusion +51us.
// Per-BLOCK redundancy is cheap (8 MB total); per-WAVE redundancy is not.
#define CNT_OFF 884736
#define GH_OFF 884800
#define CUR_OFF 901184
#define SURV_OFF 917568
#define ZERO_BYTES 32832

// Order-monotone, DISTRIBUTION-AWARE bin of the key's high word (positive
// ordered-float bits). det = max of 9 iid U[0,1) -> ~99.8% of mass in
// [0.5,1): give that range 2048 fine bins (mantissa bits 22..12); coarse
// monotone map below. Monotone at boundary: coarse max 0x3EF=1007 < 2048.
__device__ __forceinline__ u32 key_bin(u32 sb) {
    if (sb >= 0xBF800000u) return NBIN - 1;                        // det>=1: safety
    if (sb >= 0xBF000000u) return 2048u + ((sb >> 12) & 0x7FFu);   // det in [0.5,1)
    return (sb >> 20) & 0x7FFu;                                    // det in (0,0.5)
}

// Exact replica of the reference per-pixel math. FP contraction OFF for this
// TU -> float ops match numpy bit-for-bit. OOB taps read as 0.0, INCLUDING in
// the max: provably identical to the -inf-padded maxpool because scores>=0
// (zeros can't beat c>0; c==0 gives det=0 either way). Branchless.
__device__ __forceinline__ void newton_pixel(const float* __restrict__ sm, int i, int j,
                                             float& det, float& ki, float& kj, bool& valid) {
    float v[3][3];
#pragma unroll
    for (int a = 0; a < 3; ++a) {
#pragma unroll
        for (int b = 0; b < 3; ++b) {
            int ii = i + a - 1, jj = j + b - 1;
            bool in = (ii >= 0) && (ii < H_) && (jj >= 0) && (jj < W_);
            v[a][b] = in ? sm[ii * W_ + jj] : 0.0f;
        }
    }
    float c = v[1][1];
    float mx = v[0][0];
    mx = fmaxf(mx, v[0][1]); mx = fmaxf(mx, v[0][2]);
    mx = fmaxf(mx, v[1][0]); mx = fmaxf(mx, c);
    mx = fmaxf(mx, v[1][2]); mx = fmaxf(mx, v[2][0]);
    mx = fmaxf(mx, v[2][1]); mx = fmaxf(mx, v[2][2]);
    det = (mx == c) ? c : 0.0f;
    float di  = -0.5f * v[0][1] + 0.5f * v[2][1];
    float dj  = -0.5f * v[1][0] + 0.5f * v[1][2];
    float dii = v[0][1] - 2.0f * c + v[2][1];
    float djj = v[1][0] - 2.0f * c + v[1][2];
    float dij = 0.25f * v[0][0] - 0.25f * v[0][2] - 0.25f * v[2][0] + 0.25f * v[2][2];
    float dd = dii * djj - dij * dij;
    if (dd == 0.0f) dd = 1e-20f;
    float step_i = -(djj * di - dij * dj) / dd;
    float step_j = -(-dij * di + dii * dj) / dd;
    valid = (det != 0.0f) && (fabsf(step_i) < 0.5f) && (fabsf(step_j) < 0.5f);
    ki = valid ? ((float)i + step_i) : 0.0f;
    kj = valid ? ((float)j + step_j) : 0.0f;
    float i0 = floorf(ki), j0 = floorf(kj);
    valid = valid && (i0 >= 0.0f) && (j0 >= 0.0f) &&
            (i0 + 1.0f <= (float)(H_ - 1)) && (j0 + 1.0f <= (float)(W_ - 1));
}

__device__ __forceinline__ void decode_gid(u32 gid, int& s, int& i, int& j) {
    s = (int)(gid / HW_);
    int rem = (int)gid - s * HW_;
    i = rem / W_;
    j = rem - i * W_;
}

// Per-block redundant inclusive suffix scan of ghist into LDS:
// ls[b] = S[b] = #keys with bin >= b; ls[NBIN] = 0. ~16 KB L2-hot reads,
// ~2 us; cheaper than a dispatch boundary or a grid sync.
__device__ __forceinline__ void lds_suffix_scan(const u32* __restrict__ ghist,
                                                u32* ls, u32* lT) {
    int t = threadIdx.x;
    u32 chunk[16];
    u32 acc = 0;
#pragma unroll
    for (int k = 15; k >= 0; --k) {
        acc += ghist[t * 16 + k];
        chunk[k] = acc;  // suffix within chunk
    }
    lT[t] = acc;
    __syncthreads();
    // inclusive suffix scan of 256 chunk totals (Hillis-Steele)
    for (int off = 1; off < 256; off <<= 1) {
        u32 v = lT[t] + ((t + off < 256) ? lT[t + off] : 0u);
        __syncthreads();
        lT[t] = v;
        __syncthreads();
    }
    u32 add = (t < 255) ? lT[t + 1] : 0u;  // exclusive suffix of later chunks
#pragma unroll
    for (int k = 0; k < 16; ++k) ls[t * 16 + k] = chunk[k] + add;
    if (t == 0) ls[NBIN] = 0;
    __syncthreads();
}

// Kernel 1: per-pixel NMS/Newton; det maps; append valid keys; global-atomic
// score-bin histogram (~12k valid keys over ~2k hot bins -> no contention).
__global__ __launch_bounds__(256) void cand_kernel(
    const float* __restrict__ s0, const float* __restrict__ s1, const float* __restrict__ s2,
    float* __restrict__ out, u64* __restrict__ fin, u32* __restrict__ cnts,
    u32* __restrict__ ghist) {
    __shared__ u32 lcnt, base;
    int tid = threadIdx.x;
    if (tid == 0) lcnt = 0;
    __syncthreads();
    int t = blockIdx.x * 256 + tid;
    bool valid = false;
    u64 key = 0;
    {
        int s, i, j;
        decode_gid((u32)t, s, i, j);
        const float* sm = (s == 0) ? s0 : (s == 1) ? s1 : s2;
        float det, ki, kj;
        newton_pixel(sm, i, j, det, ki, kj, valid);
        out[DET_OFF + t] = det;
        if (valid) {
            u32 sb = __float_as_uint(det) | 0x80000000u;  // det>0: ordered bits
            key = ((u64)sb << 32) | (u64)(0xFFFFFFFFu - (u32)t);  // ties: lower idx first
            atomicAdd(&ghist[key_bin(sb)], 1u);
        }
    }
    u32 lpos = 0;
    if (valid) lpos = atomicAdd(&lcnt, 1u);
    __syncthreads();
    if (tid == 0 && lcnt > 0) base = atomicAdd(&cnts[0], lcnt);
    __syncthreads();
    if (valid) fin[base + lpos] = key;
}

// Kernel 2: each block privately recomputes the suffix scan in LDS, then
// scatters its grid-stride keys whose bin segment base < KMAX to
// surv[S[b+1] + cursor0[b]++] (cursor zero-based, memset-zeroed).
__global__ __launch_bounds__(256) void scatter_kernel(
    const u64* __restrict__ fin, const u32* __restrict__ ghist, u32* __restrict__ cursor,
    const u32* __restrict__ cnts, u64* __restrict__ surv) {
    __shared__ u32 ls[NBIN + 1];
    __shared__ u32 lT[256];
    lds_suffix_scan(ghist, ls, lT);
    u32 n = cnts[0];
    for (u32 idx = blockIdx.x * 256 + threadIdx.x; idx < n; idx += 64 * 256) {
        u64 key = fin[idx];
        u32 b = key_bin((u32)(key >> 32));
        u32 seglo = ls[b + 1];
        if (seglo < KMAX) {
            u32 off = atomicAdd(&cursor[b], 1u);
            surv[seglo + off] = key;
        }
    }
}

// Kernel 3: one WAVE per slot r (4 waves/block, 512 blocks). Block recomputes
// the suffix scan in LDS; each wave binary-searches the bin whose segment
// [S[b+1],S[b]) contains global rank r, identifies the rank-r key inside that
// ~13-key segment (distinct keys -> segment ranks are a permutation of
// [lo,hi): exactly one match), recomputes its newton state, and does the
// bilinear gather + L2-normalize. Slots r >= min(n,KMAX) are padding.
__global__ __launch_bounds__(256) void output_kernel(
    const u64* __restrict__ surv, const u32* __restrict__ ghist,
    const float* __restrict__ s0, const float* __restrict__ s1, const float* __restrict__ s2,
    const float* __restrict__ f0, const float* __restrict__ f1, const float* __restrict__ f2,
    float* __restrict__ out) {
    __shared__ u32 ls[NBIN + 1];
    __shared__ u32 lT[256];
    lds_suffix_scan(ghist, ls, lT);
    int tid = threadIdx.x;
    int lane = tid & 63;
    int r = blockIdx.x * 4 + (tid >> 6);
    u32 n = ls[0];
    u32 nwin = (n < KMAX) ? n : KMAX;
    if ((u32)r >= nwin) {  // padding row (wave-uniform; no more block barriers)
#pragma unroll
        for (int k = 0; k < 4; ++k) out[DESC_OFF + r * CCH + k * 64 + lane] = 0.0f;
        if (lane == 0) {
            out[SC_OFF + r] = 0.0f;
            out[KP_OFF + r * 2 + 0] = 0.0f;
            out[KP_OFF + r * 2 + 1] = 0.0f;
        }
        return;
    }
    // binary search: largest b with S[b] > r  (S non-increasing, S[0]=n>r, S[NBIN]=0)
    u32 blo = 0, bhi = NBIN;
    while (bhi - blo > 1) {
        u32 mid = (blo + bhi) >> 1;
        if (ls[mid] > (u32)r) blo = mid; else bhi = mid;
    }
    u32 b = blo;
    u32 seglo = ls[b + 1], seghi = ls[b];  // S[b+1] <= r < S[b]
    // identify the key with exact rank r (lane-strided over the segment)
    u64 mykey = 0;
    bool mine = false;
    for (u32 p = seglo + (u32)lane; p < seghi; p += 64) {
        u64 key = surv[p];
        u32 rk = seglo;
        for (u32 q = seglo; q < seghi; ++q) rk += (surv[q] > key) ? 1u : 0u;
        if (rk == (u32)r) { mykey = key; mine = true; }
    }
    u64 bal = __ballot(mine);
    int src = __ffsll((unsigned long long)bal) - 1;
    u32 klo = (u32)__shfl((int)(u32)(mykey & 0xFFFFFFFFull), src, 64);
    u32 khi = (u32)__shfl((int)(u32)(mykey >> 32), src, 64);
    u64 key = ((u64)khi << 32) | (u64)klo;
    // recompute newton state for the winner (9 broadcast loads, all lanes)
    u32 gid = 0xFFFFFFFFu - (u32)(key & 0xFFFFFFFFull);
    int s, i, j;
    decode_gid(gid, s, i, j);
    const float* sm = (s == 0) ? s0 : (s == 1) ? s1 : s2;
    float det, ki, kj;
    bool valid;
    newton_pixel(sm, i, j, det, ki, kj, valid);
    // bilinear gather + normalize: lane owns channels {lane, +64, +128, +192}
    const float* feat = (s == 0) ? f0 : (s == 1) ? f1 : f2;
    int i0 = (int)floorf(ki), j0 = (int)floorf(kj);
    float wi = ki - (float)i0;
    float wj = kj - (float)j0;
    const float* p = feat + (size_t)lane * HW_ + i0 * W_ + j0;
    float d[4];
    float sq = 0.0f;
#pragma unroll
    for (int k = 0; k < 4; ++k) {
        const float* q = p + (size_t)k * 64 * HW_;
        float f00 = q[0], f01 = q[1], f10 = q[W_], f11 = q[W_ + 1];
        d[k] = f00 * (1.0f - wi) * (1.0f - wj) + f01 * (1.0f - wi) * wj +
               f10 * wi * (1.0f - wj) + f11 * wi * wj;
        sq += d[k] * d[k];
    }
#pragma unroll
    for (int o = 1; o < 64; o <<= 1) sq += __shfl_xor(sq, o, 64);
    float norm = fmaxf(sqrtf(sq), 1e-12f);
#pragma unroll
    for (int k = 0; k < 4; ++k)
        out[DESC_OFF + r * CCH + k * 64 + lane] = d[k] / norm;
    if (lane == 0) {
        float x = kj, y = ki;
#pragma unroll
        for (int u = 0; u < 4; ++u) { x = x * 2.0f + 0.5f; y = y * 2.0f + 0.5f; }
        out[SC_OFF + r] = det;
        out[KP_OFF + r * 2 + 0] = x;  // (x=col, y=row)
        out[KP_OFF + r * 2 + 1] = y;
    }
}

extern "C" void kernel_launch(void* const* d_in, const int* in_sizes, int n_in,
                              void* d_out, int out_size, void* d_ws, size_t ws_size,
                              hipStream_t stream) {
    const float* f0 = (const float*)d_in[0];
    const float* f1 = (const float*)d_in[1];
    const float* f2 = (const float*)d_in[2];
    const float* s0 = (const float*)d_in[3];
    const float* s1 = (const float*)d_in[4];
    const float* s2 = (const float*)d_in[5];
    float* out = (float*)d_out;

    char* ws = (char*)d_ws;
    u64* fin = (u64*)ws;
    u32* cnts = (u32*)(ws + CNT_OFF);
    u32* ghist = (u32*)(ws + GH_OFF);
    u32* cursor = (u32*)(ws + CUR_OFF);
    u64* surv = (u64*)(ws + SURV_OFF);

    // zero cnts + ghist + cursor in one contiguous memset (33 KB)
    hipMemsetAsync(ws + CNT_OFF, 0, ZERO_BYTES, stream);
    cand_kernel<<<NCAND / 256, 256, 0, stream>>>(s0, s1, s2, out, fin, cnts, ghist);
    scatter_kernel<<<64, 256, 0, stream>>>(fin, ghist, cursor, cnts, surv);
    output_kernel<<<KMAX / 4, 256, 0, stream>>>(surv, ghist, s0, s1, s2, f0, f1, f2, out);
}